// Round 5
// baseline (142.041 us; speedup 1.0000x reference)
//
#include <hip/hip_runtime.h>
#include <math.h>

#define BB 8
#define TT 200
#define UU 50          // label positions; alpha lattice has U1 = 51 columns
#define VV 1024
#define U1 (UU + 1)
#define NROWS (BB * TT * U1)   // 81600 softmax rows

#define LOG2E 1.44269504088896340736f
#define LN2   0.69314718055994530942f

typedef float f4v __attribute__((ext_vector_type(4)));

// DPP wave_shr:1 — lane i gets lane i-1's value, lane 0 gets 0.
__device__ __forceinline__ float wave_shr1(float x) {
    int xi = __builtin_bit_cast(int, x);
    int r  = __builtin_amdgcn_update_dpp(0, xi, 0x138, 0xF, 0xF, true);
    return __builtin_bit_cast(float, r);
}

// ---------------- Kernel 1: row-wise logZ; emit only lp_blank & lp_emit ---------
// R2 configuration (measured 80.9 µs total): one wave per row, plain float4
// loads, label element captured in-register. Also resets k_dp's counter.
__global__ __launch_bounds__(256) void k_logp(const float* __restrict__ acts,
                                              const int* __restrict__ labels,
                                              float* __restrict__ lpb,
                                              float* __restrict__ lpe,
                                              int* __restrict__ counter) {
    if (blockIdx.x == 0 && threadIdx.x == 0) *counter = 0;
    const int wave = threadIdx.x >> 6;
    const int lane = threadIdx.x & 63;
    const int row  = blockIdx.x * 4 + wave;          // exact: grid*4 == NROWS

    int b   = row / (TT * U1);
    int rem = row - b * (TT * U1);
    int t   = rem / U1;
    int u   = rem - t * U1;
    int lab = (u < UU) ? labels[b * UU + u] : 0;     // issued before bulk loads

    const float4* p = (const float4*)(acts + (size_t)row * VV);
    float4 v0 = p[lane];
    float4 v1 = p[64 + lane];
    float4 v2 = p[128 + lane];
    float4 v3 = p[192 + lane];

    float m = fmaxf(fmaxf(fmaxf(v0.x, v0.y), fmaxf(v0.z, v0.w)),
                    fmaxf(fmaxf(v1.x, v1.y), fmaxf(v1.z, v1.w)));
    m = fmaxf(m, fmaxf(fmaxf(fmaxf(v2.x, v2.y), fmaxf(v2.z, v2.w)),
                       fmaxf(fmaxf(v3.x, v3.y), fmaxf(v3.z, v3.w))));
#pragma unroll
    for (int s = 1; s < 64; s <<= 1) m = fmaxf(m, __shfl_xor(m, s, 64));

    float sum = __expf(v0.x - m) + __expf(v0.y - m) + __expf(v0.z - m) + __expf(v0.w - m)
              + __expf(v1.x - m) + __expf(v1.y - m) + __expf(v1.z - m) + __expf(v1.w - m)
              + __expf(v2.x - m) + __expf(v2.y - m) + __expf(v2.z - m) + __expf(v2.w - m)
              + __expf(v3.x - m) + __expf(v3.y - m) + __expf(v3.z - m) + __expf(v3.w - m);
#pragma unroll
    for (int s = 1; s < 64; s <<= 1) sum += __shfl_xor(sum, s, 64);

    float logZ = m + __logf(sum);                    // all lanes hold it

    // label element ownership: element lab lives in chunk lab>>8, lane (lab>>2)&63
    int cidx = lab >> 8, lidx = (lab >> 2) & 63, eidx = lab & 3;
    float4 vs = (cidx == 0) ? v0 : (cidx == 1) ? v1 : (cidx == 2) ? v2 : v3;
    float alab = (eidx & 2) ? ((eidx & 1) ? vs.w : vs.z)
                            : ((eidx & 1) ? vs.y : vs.x);
    if (u < UU && lane == lidx) lpe[(b * TT + t) * UU + u] = alab - logZ;
    if (lane == 0)              lpb[row] = v0.x - logZ;
}

// ---------------- Kernel 2: anti-diagonal DP + fused final reduction ------------
// One block per batch. 1024 threads stage lpb/lpe (base-2 scaled) into LDS,
// wave 0 walks the 250 diagonals; the last block to finish sums all 8
// log-likelihoods and writes the output (device-scope atomics + fences).
__global__ __launch_bounds__(1024) void k_dp(const float* __restrict__ lpb,
                                             const float* __restrict__ lpe,
                                             const int* __restrict__ act_lens,
                                             const int* __restrict__ label_lens,
                                             float* __restrict__ loglike,
                                             int* __restrict__ counter,
                                             float* __restrict__ out) {
    __shared__ __align__(16) float s_lpb[TT * U1];   // 40.8 KB
    __shared__ __align__(16) float s_lpe[TT * UU];   // 40.0 KB

    const int b = blockIdx.x;
    const f4v* gb4 = (const f4v*)(lpb + (size_t)b * TT * U1);
    const f4v* ge4 = (const f4v*)(lpe + (size_t)b * TT * UU);
    f4v* sb4 = (f4v*)s_lpb;
    f4v* se4 = (f4v*)s_lpe;
    for (int i = threadIdx.x; i < TT * U1 / 4; i += 1024) {
        f4v v = gb4[i];
        sb4[i] = v * LOG2E;
    }
    for (int i = threadIdx.x; i < TT * UU / 4; i += 1024) {
        f4v v = ge4[i];
        se4[i] = v * LOG2E;
    }
    __syncthreads();
    if (threadIdx.x >= 64) return;

    const int u  = threadIdx.x;        // lane == u; lanes 51..63 carry -inf
    const int uc = min(u, UU);
    const int tl = act_lens[b] - 1;
    const int ul = label_lens[b];
    const int dtgt = tl + ul;
    const float NEG = -INFINITY;
    const float bsave = s_lpb[tl * U1 + ul];

    float Aprev = (u == 0) ? 0.0f : NEG;
    float saved = (dtgt == 0 && u == 0) ? bsave : NEG;

#pragma unroll 10
    for (int d = 1; d <= TT - 1 + UU; ++d) {
        float Aup = wave_shr1(Aprev);
        int t  = d - u;
        int tb = min(max(t - 1, 0), TT - 1);
        int te = min(max(t, 0), TT - 1);
        float bv = s_lpb[tb * U1 + uc];
        float ev = s_lpe[te * UU + max(uc - 1, 0)];
        bool cellok = (t >= 0) & (t < TT) & (u <= UU);
        float ft = (cellok & (t >= 1)) ? Aprev + bv : NEG;
        float em = (cellok & (u >= 1)) ? Aup + ev   : NEG;
        float mm = fmaxf(ft, em);
        float dd = fminf(ft, em) - mm;
        float A  = mm + __builtin_amdgcn_logf(1.0f + __builtin_amdgcn_exp2f(dd));
        A = cellok ? A : NEG;
        saved = (d == dtgt && u == ul) ? A + bsave : saved;
        Aprev = A;
    }

    // publish this batch's log-likelihood, last block reduces
    int old = 0;
    if (u == ul) {
        atomicExch(&loglike[b], saved * LN2);   // device-scope store
        __threadfence();
        old = atomicAdd(counter, 1);
    }
    old = __shfl(old, ul, 64);                  // broadcast from lane ul
    if (old == BB - 1) {
        __threadfence();
        float v = (u < BB) ? atomicAdd(&loglike[u], 0.0f) : 0.0f;
#pragma unroll
        for (int s = 1; s < 8; s <<= 1) v += __shfl_xor(v, s, 64);
        if (u == 0) out[0] = -v;
    }
}

extern "C" void kernel_launch(void* const* d_in, const int* in_sizes, int n_in,
                              void* d_out, int out_size, void* d_ws, size_t ws_size,
                              hipStream_t stream) {
    const float* acts       = (const float*)d_in[0];
    const int*   labels     = (const int*)d_in[1];
    const int*   act_lens   = (const int*)d_in[2];
    const int*   label_lens = (const int*)d_in[3];

    float* ws  = (float*)d_ws;
    float* lpb = ws;                         // B*T*U1  = 81600 floats
    float* lpe = lpb + NROWS;                // B*T*U   = 80000 floats
    float* ll  = lpe + BB * TT * UU;         // B       = 8 floats
    int*   cnt = (int*)(ll + BB);            // 1 int
    float* out = (float*)d_out;

    k_logp<<<NROWS / 4, 256, 0, stream>>>(acts, labels, lpb, lpe, cnt);
    k_dp<<<BB, 1024, 0, stream>>>(lpb, lpe, act_lens, label_lens, ll, cnt, out);
}

// Round 6
// 80.471 us; speedup vs baseline: 1.7651x; 1.7651x over previous
//
#include <hip/hip_runtime.h>
#include <math.h>

#define BB 8
#define TT 200
#define UU 50          // label positions; alpha lattice has U1 = 51 columns
#define VV 1024
#define U1 (UU + 1)
#define NROWS (BB * TT * U1)   // 81600 softmax rows

#define LOG2E 1.44269504088896340736f
#define LN2   0.69314718055994530942f

// DPP wave_shr:1 — lane i gets lane i-1's value, lane 0 gets 0.
__device__ __forceinline__ float wave_shr1(float x) {
    int xi = __builtin_bit_cast(int, x);
    int r  = __builtin_amdgcn_update_dpp(0, xi, 0x138, 0xF, 0xF, true);
    return __builtin_bit_cast(float, r);
}

// ---------------- Kernel 1: row-wise logZ; emit only lp_blank & lp_emit ---------
// One wave (64 lanes) per row of V=1024 floats. 4 waves / 256-thread block.
// Label element captured during the main coalesced load (no dependent re-read).
__global__ __launch_bounds__(256) void k_logp(const float* __restrict__ acts,
                                              const int* __restrict__ labels,
                                              float* __restrict__ lpb,
                                              float* __restrict__ lpe) {
    const int wave = threadIdx.x >> 6;
    const int lane = threadIdx.x & 63;
    const int row  = blockIdx.x * 4 + wave;          // exact: grid*4 == NROWS

    int b   = row / (TT * U1);
    int rem = row - b * (TT * U1);
    int t   = rem / U1;
    int u   = rem - t * U1;
    int lab = (u < UU) ? labels[b * UU + u] : 0;     // issued before bulk loads

    const float4* p = (const float4*)(acts + (size_t)row * VV);
    float4 v0 = p[lane];
    float4 v1 = p[64 + lane];
    float4 v2 = p[128 + lane];
    float4 v3 = p[192 + lane];

    float m = fmaxf(fmaxf(fmaxf(v0.x, v0.y), fmaxf(v0.z, v0.w)),
                    fmaxf(fmaxf(v1.x, v1.y), fmaxf(v1.z, v1.w)));
    m = fmaxf(m, fmaxf(fmaxf(fmaxf(v2.x, v2.y), fmaxf(v2.z, v2.w)),
                       fmaxf(fmaxf(v3.x, v3.y), fmaxf(v3.z, v3.w))));
#pragma unroll
    for (int s = 1; s < 64; s <<= 1) m = fmaxf(m, __shfl_xor(m, s, 64));

    float sum = __expf(v0.x - m) + __expf(v0.y - m) + __expf(v0.z - m) + __expf(v0.w - m)
              + __expf(v1.x - m) + __expf(v1.y - m) + __expf(v1.z - m) + __expf(v1.w - m)
              + __expf(v2.x - m) + __expf(v2.y - m) + __expf(v2.z - m) + __expf(v2.w - m)
              + __expf(v3.x - m) + __expf(v3.y - m) + __expf(v3.z - m) + __expf(v3.w - m);
#pragma unroll
    for (int s = 1; s < 64; s <<= 1) sum += __shfl_xor(sum, s, 64);

    float logZ = m + __logf(sum);                    // all lanes hold it

    // label element ownership: element lab lives in chunk lab>>8, lane (lab>>2)&63
    int cidx = lab >> 8, lidx = (lab >> 2) & 63, eidx = lab & 3;
    float4 vs = (cidx == 0) ? v0 : (cidx == 1) ? v1 : (cidx == 2) ? v2 : v3;
    float alab = (eidx & 2) ? ((eidx & 1) ? vs.w : vs.z)
                            : ((eidx & 1) ? vs.y : vs.x);
    if (u < UU && lane == lidx) lpe[(b * TT + t) * UU + u] = alab - logZ;
    if (lane == 0)              lpb[row] = v0.x - logZ;
}

// ---------------- Kernel 2: anti-diagonal wavefront alpha DP --------------------
// One block per batch element. 256 threads stage lpb/lpe (pre-scaled to base-2
// log domain) into LDS, then wave 0 (lane == u) walks the 250 diagonals.
__global__ __launch_bounds__(256) void k_dp(const float* __restrict__ lpb,
                                            const float* __restrict__ lpe,
                                            const int* __restrict__ act_lens,
                                            const int* __restrict__ label_lens,
                                            float* __restrict__ loglike) {
    __shared__ __align__(16) float s_lpb[TT * U1];   // 40.8 KB
    __shared__ __align__(16) float s_lpe[TT * UU];   // 40.0 KB

    const int b = blockIdx.x;
    const float4* gb4 = (const float4*)(lpb + (size_t)b * TT * U1);
    const float4* ge4 = (const float4*)(lpe + (size_t)b * TT * UU);
    float4* sb4 = (float4*)s_lpb;
    float4* se4 = (float4*)s_lpe;
    for (int i = threadIdx.x; i < TT * U1 / 4; i += 256) {
        float4 v = gb4[i];
        v.x *= LOG2E; v.y *= LOG2E; v.z *= LOG2E; v.w *= LOG2E;
        sb4[i] = v;
    }
    for (int i = threadIdx.x; i < TT * UU / 4; i += 256) {
        float4 v = ge4[i];
        v.x *= LOG2E; v.y *= LOG2E; v.z *= LOG2E; v.w *= LOG2E;
        se4[i] = v;
    }
    __syncthreads();
    if (threadIdx.x >= 64) return;

    const int u  = threadIdx.x;        // lane == u; lanes 51..63 carry -inf
    const int uc = min(u, UU);
    const int tl = act_lens[b] - 1;
    const int ul = label_lens[b];
    const int dtgt = tl + ul;
    const float NEG = -INFINITY;
    const float bsave = s_lpb[tl * U1 + ul];

    float Aprev = (u == 0) ? 0.0f : NEG;
    float saved = (dtgt == 0 && u == 0) ? bsave : NEG;

#pragma unroll 5
    for (int d = 1; d <= TT - 1 + UU; ++d) {
        float Aup = wave_shr1(Aprev);
        int t  = d - u;
        int tb = min(max(t - 1, 0), TT - 1);
        int te = min(max(t, 0), TT - 1);
        float bv = s_lpb[tb * U1 + uc];
        float ev = s_lpe[te * UU + max(uc - 1, 0)];
        bool cellok = (t >= 0) & (t < TT) & (u <= UU);
        float ft = (cellok & (t >= 1)) ? Aprev + bv : NEG;
        float em = (cellok & (u >= 1)) ? Aup + ev   : NEG;
        float mm = fmaxf(ft, em);
        float dd = fminf(ft, em) - mm;
        float A  = mm + __builtin_amdgcn_logf(1.0f + __builtin_amdgcn_exp2f(dd));
        A = cellok ? A : NEG;
        saved = (d == dtgt && u == ul) ? A + bsave : saved;
        Aprev = A;
    }
    if (u == ul) loglike[b] = saved * LN2;
}

// ---------------- Kernel 3: final reduction -------------------------------------
__global__ void k_sum(const float* __restrict__ loglike, float* __restrict__ out) {
    if (threadIdx.x == 0) {
        float s = 0.0f;
        for (int i = 0; i < BB; ++i) s += loglike[i];
        out[0] = -s;
    }
}

extern "C" void kernel_launch(void* const* d_in, const int* in_sizes, int n_in,
                              void* d_out, int out_size, void* d_ws, size_t ws_size,
                              hipStream_t stream) {
    const float* acts       = (const float*)d_in[0];
    const int*   labels     = (const int*)d_in[1];
    const int*   act_lens   = (const int*)d_in[2];
    const int*   label_lens = (const int*)d_in[3];

    float* ws  = (float*)d_ws;
    float* lpb = ws;                         // B*T*U1  = 81600 floats
    float* lpe = lpb + NROWS;                // B*T*U   = 80000 floats
    float* ll  = lpe + BB * TT * UU;         // B       = 8 floats
    float* out = (float*)d_out;

    k_logp<<<NROWS / 4, 256, 0, stream>>>(acts, labels, lpb, lpe);
    k_dp<<<BB, 256, 0, stream>>>(lpb, lpe, act_lens, label_lens, ll);
    k_sum<<<1, 64, 0, stream>>>(ll, out);
}